// Round 13
// baseline (1399.951 us; speedup 1.0000x reference)
//
#include <hip/hip_runtime.h>
#include <hip/hip_bf16.h>

// Problem dims
constexpr int NB = 32, NS = 512, NE = 256, NC = 128, NHD = 256, NG = 1024, NT = 16, NH = 512;

typedef float f32x4 __attribute__((ext_vector_type(4)));

// ---------------- helpers ----------------
__device__ __forceinline__ unsigned short f2bf(float f) {
    unsigned u = __float_as_uint(f);
    u += 0x7fffu + ((u >> 16) & 1u);
    return (unsigned short)(u >> 16);
}
__device__ __forceinline__ float bf2f(unsigned short s) {
    return __uint_as_float(((unsigned)s) << 16);
}
__device__ __forceinline__ float vexp2(float x) {
    float r; asm("v_exp_f32 %0, %1" : "=v"(r) : "v"(x)); return r;
}
__device__ __forceinline__ float vrcp(float x) {
    float r; asm("v_rcp_f32 %0, %1" : "=v"(r) : "v"(x)); return r;
}
__device__ __forceinline__ float vlog2(float x) {
    float r; asm("v_log_f32 %0, %1" : "=v"(r) : "v"(x)); return r;
}
__device__ __forceinline__ unsigned char f2fp8(float v) {
    int r = __builtin_amdgcn_cvt_pk_fp8_f32(v, 0.f, 0, false);
    return (unsigned char)(r & 0xff);
}
// gate pre-activation scale factors (i,f,o: sigm -> -log2(e); g: tanh -> +2*log2(e))
__device__ __constant__ float KSC[4] = {-1.442695041f, -1.442695041f, 2.885390082f, -1.442695041f};

// ---------------- prep: weight transposes ----------------
// wT[e3][c] = conv_w[c][e3]   (e3 = e*3+k, 768x128)
__global__ void k_prep_convw(const float* __restrict__ w, float* __restrict__ wT) {
    int i = blockIdx.x * 256 + threadIdx.x;
    if (i >= 768 * 128) return;
    int e3 = i >> 7, c = i & 127;
    wT[i] = w[c * 768 + e3];
}

// per-(cell,gate)-column absmax scale: scale[d][j*4+g] = max_k |whh| / 448
__global__ void k_prep_scale(const float* __restrict__ whh_f, const float* __restrict__ whh_b,
                             float* __restrict__ scale) {
    int d = blockIdx.y;
    const float* src = d ? whh_b : whh_f;
    int col = blockIdx.x * 256 + threadIdx.x;  // 0..1023
    if (col >= 1024) return;
    int j = col >> 2, g = col & 3;
    const float* p = src + (size_t)(g * 256 + j) * 256;
    float m = 0.f;
    for (int k = 0; k < 256; ++k) m = fmaxf(m, fabsf(p[k]));
    scale[d * 1024 + col] = (m > 0.f) ? (m * (1.f / 448.f)) : 1.f;
}

// fp8 MFMA B-fragment layout for whh (16-wave config):
// idx bits (LSB->MSB): e:3 | lane:6 | g:2 | kt:3 | w:4 | d:1   (1 byte each)
// j = w*16 + (lane&15); k = kt*32 + (lane>>4)*8 + e
// value = e4m3( whh_d[(g*256+j)*256+k] / scale[d][j*4+g] )
__global__ void k_prep_whh_frag8(const float* __restrict__ whh_f, const float* __restrict__ whh_b,
                                 const float* __restrict__ scale, unsigned char* __restrict__ whhF8) {
    int i = blockIdx.x * 256 + threadIdx.x;
    if (i >= (1 << 19)) return;
    int e = i & 7;
    int lane = (i >> 3) & 63;
    int g = (i >> 9) & 3;
    int kt = (i >> 11) & 7;
    int w = (i >> 14) & 15;
    int d = (i >> 18) & 1;
    const float* src = d ? whh_b : whh_f;
    int j = w * 16 + (lane & 15);
    int k = kt * 32 + (lane >> 4) * 8 + e;
    float sc = scale[d * 1024 + j * 4 + g];
    float v = src[(g * 256 + j) * 256 + k] / sc;
    whhF8[i] = f2fp8(v);
}

// wihT[d][(e*256+j)*4+g] = wih_d[(g*256+j)*128+e]  (f32)
__global__ void k_prep_wih(const float* __restrict__ wih_f, const float* __restrict__ wih_b,
                           float* __restrict__ wihT) {
    int d = blockIdx.y;
    const float* src = d ? wih_b : wih_f;
    int i = blockIdx.x * 256 + threadIdx.x;
    if (i >= NC * NG) return;
    int g = i & 3, j = (i >> 2) & 255, e = i >> 10;
    wihT[(size_t)d * NC * NG + i] = src[(g * 256 + j) * 128 + e];
}

// bias2[d][j*4+g] = bih[g*256+j] + bhh[g*256+j]
__global__ void k_prep_bias(const float* __restrict__ bih_f, const float* __restrict__ bhh_f,
                            const float* __restrict__ bih_b, const float* __restrict__ bhh_b,
                            float* __restrict__ bias2) {
    int d = blockIdx.y;
    const float* bi = d ? bih_b : bih_f;
    const float* bh = d ? bhh_b : bhh_f;
    int i = blockIdx.x * 256 + threadIdx.x;
    if (i >= NG) return;
    int g = i & 3, j = i >> 2;
    bias2[(size_t)d * NG + i] = bi[g * 256 + j] + bh[g * 256 + j];
}

// ---------------- embedding + conv1d(k=3,pad=1) + relu ----------------
__global__ __launch_bounds__(128) void k_conv(const int* __restrict__ x,
                                              const float* __restrict__ table,
                                              const float* __restrict__ wT,
                                              const float* __restrict__ conv_b,
                                              float* __restrict__ feat) {
    int b = blockIdx.y;
    int s0 = blockIdx.x * 8;
    int c = threadIdx.x;
    __shared__ float win[10][NE];
    for (int i = 0; i < 10; ++i) {
        int s = s0 - 1 + i;
        if (s < 0 || s >= NS) {
            for (int e = c; e < NE; e += 128) win[i][e] = 0.f;
        } else {
            int tok = x[b * NS + s];
            const float* row = table + (size_t)tok * NE;
            for (int e = c; e < NE; e += 128) win[i][e] = row[e];
        }
    }
    __syncthreads();
    float acc[8];
    float bc = conv_b[c];
#pragma unroll
    for (int p = 0; p < 8; ++p) acc[p] = bc;
    for (int e = 0; e < NE; ++e) {
        float r[10];
#pragma unroll
        for (int i = 0; i < 10; ++i) r[i] = win[i][e];
#pragma unroll
        for (int k = 0; k < 3; ++k) {
            float wv = wT[(e * 3 + k) * NC + c];
#pragma unroll
            for (int p = 0; p < 8; ++p) acc[p] += wv * r[p + k];
        }
    }
#pragma unroll
    for (int p = 0; p < 8; ++p) {
        feat[((size_t)b * NS + s0 + p) * NC + c] = fmaxf(acc[p], 0.f);
    }
}

// ---------------- input-side gates (PRE-SCALED by KSC): xg bf16 ----------------
__global__ __launch_bounds__(256) void k_xgate(const float* __restrict__ feat,
                                               const float* __restrict__ wihT,
                                               const float* __restrict__ bias2,
                                               unsigned short* __restrict__ xg) {
    int d = blockIdx.y;
    int p0 = blockIdx.x * 16;  // pair idx = s*NB + b
    int j = threadIdx.x;
    __shared__ float fv[16][NC];
    for (int i = threadIdx.x; i < 16 * NC; i += 256) {
        int p = i >> 7, e = i & 127;
        int idx = p0 + p;
        int s = idx >> 5, b = idx & 31;
        fv[p][e] = feat[((size_t)b * NS + s) * NC + e];
    }
    __syncthreads();
    const float* W = wihT + (size_t)d * NC * NG;
    float b0 = bias2[(size_t)d * NG + j * 4 + 0];
    float b1 = bias2[(size_t)d * NG + j * 4 + 1];
    float b2 = bias2[(size_t)d * NG + j * 4 + 2];
    float b3 = bias2[(size_t)d * NG + j * 4 + 3];
    float acc[16][4];
#pragma unroll
    for (int p = 0; p < 16; ++p) {
        acc[p][0] = b0; acc[p][1] = b1; acc[p][2] = b2; acc[p][3] = b3;
    }
    for (int e = 0; e < NC; ++e) {
        float4 w4 = *(const float4*)(W + ((size_t)e * 256 + j) * 4);
#pragma unroll
        for (int p = 0; p < 16; ++p) {
            float fe = fv[p][e];
            acc[p][0] += fe * w4.x;
            acc[p][1] += fe * w4.y;
            acc[p][2] += fe * w4.z;
            acc[p][3] += fe * w4.w;
        }
    }
#pragma unroll
    for (int p = 0; p < 16; ++p) {
        ushort4 o;
        o.x = f2bf(acc[p][0] * KSC[0]); o.y = f2bf(acc[p][1] * KSC[1]);
        o.z = f2bf(acc[p][2] * KSC[2]); o.w = f2bf(acc[p][3] * KSC[3]);
        unsigned short* dst = xg + (size_t)d * NS * NB * NG + ((size_t)(p0 + p) * 256 + j) * 4;
        *(ushort4*)dst = o;
    }
}

// ---------------- LSTM recurrence: fp8 MFMA, W register-resident, 8-way batch-split ----------
// grid = 8 blocks: d = bid>>2, bq = bid&3 (batch quarter, 8 batches each). 1024 thr = 16 waves.
// Round-12 insight: per-SIMD MFMA cost is ~19.4 cyc/inst -> 4-block split had 2490 cyc/step of
// matrix pipe per CU. 8 blocks halve per-CU MFMA (1245) at the cost of idle A-rows 8..15 and
// exec-masked epilogue lanes (lq>=2) -- attacks the MFMA term, leaves VALU-issue as next wall.
__global__ __launch_bounds__(1024, 1) void k_lstm2(const unsigned char* __restrict__ whhF8,
                                                   const float* __restrict__ scale,
                                                   const unsigned short* __restrict__ xg,
                                                   float* __restrict__ hcat) {
    int bid = blockIdx.x;
    int d = bid >> 2, bq = bid & 3;
    int tid = threadIdx.x;
    int w = tid >> 6, l = tid & 63;
    int l15 = l & 15, lq = l >> 4;
    bool act = (lq < 2);  // lanes owning valid batch rows (0..7)
    __shared__ unsigned char hbuf[2][16][280];  // rows 8..15 stay zero forever
    for (int i = tid; i < 2 * 16 * 280; i += 1024) (&hbuf[0][0][0])[i] = 0;
    // preload fp8 W fragments: 32 frags x 1 u64 = 64 regs/thread (replicated per block)
    unsigned long long wf[32];
    const unsigned char* wp = whhF8 + ((size_t)(d * 16 + w) << 14) + (size_t)l * 8;
#pragma unroll
    for (int f = 0; f < 32; ++f) wf[f] = *(const unsigned long long*)(wp + f * 512);
    int cell = w * 16 + l15;  // the one cell this lane owns
    float csc[4];
#pragma unroll
    for (int g = 0; g < 4; ++g)
        csc[g] = scale[d * 1024 + cell * 4 + g] * KSC[g];
    const unsigned short* XG = xg + (size_t)d * NS * NB * NG;
    float cst[4] = {};
    __syncthreads();
    int cur = 0;
    // prefetch xg for step 0 (batches bq*8 + lq*4 + r, valid only for act lanes)
    unsigned long long xq[4] = {};
    if (act) {
        int s0 = d ? (NS - 1) : 0;
#pragma unroll
        for (int r = 0; r < 4; ++r)
            xq[r] = *(const unsigned long long*)(
                XG + (size_t)(s0 * 32 + bq * 8 + lq * 4 + r) * 1024 + cell * 4);
    }
    for (int step = 0; step < NS; ++step) {
        int s = d ? (NS - 1 - step) : step;
        // issue next step's xg loads (full step of latency cover)
        unsigned long long xn[4] = {};
        if (act) {
            int stn = (step + 1 < NS) ? step + 1 : step;
            int sn = d ? (NS - 1 - stn) : stn;
#pragma unroll
            for (int r = 0; r < 4; ++r)
                xn[r] = *(const unsigned long long*)(
                    XG + (size_t)(sn * 32 + bq * 8 + lq * 4 + r) * 1024 + cell * 4);
        }
        // MFMA: gates[8(16) x 64] for this wave's 16 cells = h[8 x 256] @ Wslice
        f32x4 acc[4];
#pragma unroll
        for (int g = 0; g < 4; ++g) acc[g] = (f32x4){0.f, 0.f, 0.f, 0.f};
#pragma unroll
        for (int kt = 0; kt < 8; ++kt) {
            unsigned long long a = *(const unsigned long long*)&hbuf[cur][l15][kt * 32 + lq * 8];
#pragma unroll
            for (int g = 0; g < 4; ++g)
                acc[g] = __builtin_amdgcn_mfma_f32_16x16x32_fp8_fp8(
                    (long long)a, (long long)wf[kt * 4 + g], acc[g], 0, 0, 0);
        }
        // epilogue: one cell x 4 batches per act lane; pre-scaled gates, asm trans
        int nxt = cur ^ 1;
        if (act) {
#pragma unroll
            for (int r = 0; r < 4; ++r) {
                unsigned long long xv = xq[r];
                float pi = fmaf(acc[0][r], csc[0], bf2f((unsigned short)xv));
                float pf = fmaf(acc[1][r], csc[1], bf2f((unsigned short)(xv >> 16)));
                float pg = fmaf(acc[2][r], csc[2], bf2f((unsigned short)(xv >> 32)));
                float po = fmaf(acc[3][r], csc[3], bf2f((unsigned short)(xv >> 48)));
                float si = vrcp(1.f + vexp2(pi));
                float sf = vrcp(1.f + vexp2(pf));
                float tg = fmaf(-2.f, vrcp(1.f + vexp2(pg)), 1.f);
                float so = vrcp(1.f + vexp2(po));
                float c = fmaf(sf, cst[r], si * tg);
                cst[r] = c;
                float tc = fmaf(-2.f, vrcp(1.f + vexp2(2.885390082f * c)), 1.f);
                float h = so * tc;
                int b = lq * 4 + r;  // local batch row 0..7
                __builtin_nontemporal_store(h,
                    hcat + (size_t)(s * 32 + bq * 8 + b) * NH + d * NHD + cell);
                hbuf[nxt][b][cell] = f2fp8(h);
            }
        }
        __syncthreads();
        cur = nxt;
#pragma unroll
        for (int r = 0; r < 4; ++r) xq[r] = xn[r];
    }
}

// ---------------- FC to emissions: em[s][b][t] ----------------
__global__ __launch_bounds__(256) void k_fc(const float* __restrict__ hcat,
                                            const float* __restrict__ fc_w,
                                            const float* __restrict__ fc_b,
                                            float* __restrict__ em) {
    int p0 = blockIdx.x * 16;  // 16 pairs (s*NB+b linear)
    __shared__ float hv[16][NH];
    for (int i = threadIdx.x; i < 16 * NH; i += 256) {
        int p = i >> 9, hh = i & 511;
        hv[p][hh] = hcat[(size_t)(p0 + p) * NH + hh];
    }
    __syncthreads();
    int p = threadIdx.x >> 4, t = threadIdx.x & 15;
    const float* fw = fc_w + t * NH;
    float acc = fc_b[t];
#pragma unroll 8
    for (int hh = 0; hh < NH; ++hh) acc += hv[p][hh] * fw[hh];
    em[(size_t)(p0 + p) * NT + t] = acc;
}

// ---------------- CRF NLL per batch: wave-parallel forward algorithm ----------------
__global__ __launch_bounds__(64) void k_crf(const float* __restrict__ em,
                                            const int* __restrict__ tags,
                                            const int* __restrict__ mask,
                                            const float* __restrict__ start_t,
                                            const float* __restrict__ end_t,
                                            const float* __restrict__ trans,
                                            float* __restrict__ res) {
    int b = blockIdx.x;
    int tid = threadIdx.x;
    __shared__ float em_sh[NS * NT];   // 32 KB
    __shared__ float tr[NT * NT];
    __shared__ float alpha_sh[NT];
    __shared__ float msk[NS];
    __shared__ float sc_sh;
    for (int i = tid; i < NT * NT; i += 64) tr[i] = trans[i];
    for (int i = tid; i < NS * NT; i += 64) {
        int s = i >> 4, t = i & 15;
        em_sh[i] = em[((size_t)s * NB + b) * NT + t];
    }
    for (int s = tid; s < NS; s += 64) msk[s] = (float)mask[b * NS + s];
    __syncthreads();
    float part = 0.f, msum = 0.f;
    for (int s = tid; s < NS; s += 64) msum += msk[s];
    for (int s = 1 + tid; s < NS; s += 64) {
        int pv = tags[b * NS + s - 1], cu = tags[b * NS + s];
        part += (tr[pv * NT + cu] + em_sh[s * NT + cu]) * msk[s];
    }
#pragma unroll
    for (int o = 32; o > 0; o >>= 1) {
        part += __shfl_down(part, o);
        msum += __shfl_down(msum, o);
    }
    if (tid == 0) {
        int t0 = tags[b * NS];
        int send = (int)msum - 1;
        sc_sh = start_t[t0] + em_sh[t0] + part + end_t[tags[b * NS + send]];
    }
    if (tid < NT) alpha_sh[tid] = start_t[tid] + em_sh[tid];
    __syncthreads();
    int t_to = tid >> 2, q = tid & 3;
    for (int s = 1; s < NS; ++s) {
        float v0 = alpha_sh[q * 4 + 0] + tr[(q * 4 + 0) * NT + t_to];
        float v1 = alpha_sh[q * 4 + 1] + tr[(q * 4 + 1) * NT + t_to];
        float v2 = alpha_sh[q * 4 + 2] + tr[(q * 4 + 2) * NT + t_to];
        float v3 = alpha_sh[q * 4 + 3] + tr[(q * 4 + 3) * NT + t_to];
        float mx = fmaxf(fmaxf(v0, v1), fmaxf(v2, v3));
        mx = fmaxf(mx, __shfl_xor(mx, 1));
        mx = fmaxf(mx, __shfl_xor(mx, 2));
        float nmx = -1.442695041f * mx;
        float ss = vexp2(fmaf(v0, 1.442695041f, nmx)) + vexp2(fmaf(v1, 1.442695041f, nmx))
                 + vexp2(fmaf(v2, 1.442695041f, nmx)) + vexp2(fmaf(v3, 1.442695041f, nmx));
        ss += __shfl_xor(ss, 1);
        ss += __shfl_xor(ss, 2);
        float nv = mx + 0.6931471806f * vlog2(ss) + em_sh[s * NT + t_to];
        float old = alpha_sh[t_to];
        nv = (msk[s] > 0.f) ? nv : old;
        __syncthreads();
        if (q == 0) alpha_sh[t_to] = nv;
        __syncthreads();
    }
    if (tid == 0) {
        float mx = -1e30f;
        for (int t = 0; t < NT; ++t) mx = fmaxf(mx, alpha_sh[t] + end_t[t]);
        float sum = 0.f;
        for (int t = 0; t < NT; ++t) sum += vexp2(1.442695041f * (alpha_sh[t] + end_t[t] - mx));
        res[b] = sc_sh - (mx + 0.6931471806f * vlog2(sum));
    }
}

__global__ void k_final(const float* __restrict__ res, float* __restrict__ out) {
    int tid = threadIdx.x;
    float v = (tid < NB) ? res[tid] : 0.f;
#pragma unroll
    for (int o = 32; o > 0; o >>= 1) v += __shfl_down(v, o);
    if (tid == 0) out[0] = -v / NB;
}

// ---------------- workspace layout ----------------
constexpr size_t SZ_FEAT  = (size_t)NB * NS * NC * 4;       // 8 MB
constexpr size_t SZ_WT    = (size_t)768 * 128 * 4;          // 384 KB
constexpr size_t SZ_WHHF8 = (size_t)(1 << 19);              // 512 KB (fp8 frags)
constexpr size_t SZ_SCALE = (size_t)2 * 1024 * 4;           // 8 KB
constexpr size_t SZ_WIHT  = (size_t)2 * NC * NG * 4;        // 1 MB
constexpr size_t SZ_BIAS  = (size_t)2 * NG * 4;             // 8 KB
constexpr size_t SZ_XG    = (size_t)2 * NS * NB * NG * 2;   // 64 MB (bf16)
constexpr size_t SZ_HCAT  = (size_t)NS * NB * NH * 4;       // 32 MB
constexpr size_t SZ_EM    = (size_t)NS * NB * NT * 4;       // 1 MB

constexpr size_t OFF_FEAT  = 0;
constexpr size_t OFF_WT    = OFF_FEAT + SZ_FEAT;
constexpr size_t OFF_WHHF8 = OFF_WT + SZ_WT;
constexpr size_t OFF_SCALE = OFF_WHHF8 + SZ_WHHF8;
constexpr size_t OFF_WIHT  = OFF_SCALE + SZ_SCALE;
constexpr size_t OFF_BIAS  = OFF_WIHT + SZ_WIHT;
constexpr size_t OFF_XG    = OFF_BIAS + SZ_BIAS;
constexpr size_t OFF_HCAT  = OFF_XG + SZ_XG;
constexpr size_t OFF_EM    = OFF_HCAT + SZ_HCAT;
constexpr size_t OFF_RES   = OFF_EM + SZ_EM;

extern "C" void kernel_launch(void* const* d_in, const int* in_sizes, int n_in,
                              void* d_out, int out_size, void* d_ws, size_t ws_size,
                              hipStream_t stream) {
    const int* x        = (const int*)d_in[0];
    const int* mask     = (const int*)d_in[1];
    const int* tags     = (const int*)d_in[2];
    const float* table  = (const float*)d_in[3];
    const float* conv_w = (const float*)d_in[4];
    const float* conv_b = (const float*)d_in[5];
    const float* wih_f  = (const float*)d_in[6];
    const float* whh_f  = (const float*)d_in[7];
    const float* bih_f  = (const float*)d_in[8];
    const float* bhh_f  = (const float*)d_in[9];
    const float* wih_b  = (const float*)d_in[10];
    const float* whh_b  = (const float*)d_in[11];
    const float* bih_b  = (const float*)d_in[12];
    const float* bhh_b  = (const float*)d_in[13];
    const float* fc_w   = (const float*)d_in[14];
    const float* fc_b   = (const float*)d_in[15];
    const float* start_t = (const float*)d_in[16];
    const float* end_t  = (const float*)d_in[17];
    const float* trans  = (const float*)d_in[18];

    char* ws = (char*)d_ws;
    float* feat = (float*)(ws + OFF_FEAT);
    float* wT   = (float*)(ws + OFF_WT);
    unsigned char* whhF8 = (unsigned char*)(ws + OFF_WHHF8);
    float* scale = (float*)(ws + OFF_SCALE);
    float* wihT = (float*)(ws + OFF_WIHT);
    float* bias2 = (float*)(ws + OFF_BIAS);
    unsigned short* xg = (unsigned short*)(ws + OFF_XG);
    float* hcat = (float*)(ws + OFF_HCAT);
    float* em   = (float*)(ws + OFF_EM);
    float* res  = (float*)(ws + OFF_RES);

    k_prep_convw<<<dim3(384), 256, 0, stream>>>(conv_w, wT);
    k_prep_scale<<<dim3(4, 2), 256, 0, stream>>>(whh_f, whh_b, scale);
    k_prep_whh_frag8<<<dim3(2048), 256, 0, stream>>>(whh_f, whh_b, scale, whhF8);
    k_prep_wih<<<dim3(512, 2), 256, 0, stream>>>(wih_f, wih_b, wihT);
    k_prep_bias<<<dim3(4, 2), 256, 0, stream>>>(bih_f, bhh_f, bih_b, bhh_b, bias2);
    k_conv<<<dim3(NS / 8, NB), 128, 0, stream>>>(x, table, wT, conv_b, feat);
    k_xgate<<<dim3(NS * NB / 16, 2), 256, 0, stream>>>(feat, wihT, bias2, xg);
    k_lstm2<<<dim3(8), 1024, 0, stream>>>(whhF8, scale, xg, hcat);
    k_fc<<<dim3(NS * NB / 16), 256, 0, stream>>>(hcat, fc_w, fc_b, em);
    k_crf<<<dim3(NB), 64, 0, stream>>>(em, tags, mask, start_t, end_t, trans, res);
    k_final<<<dim3(1), 64, 0, stream>>>(res, (float*)d_out);
}

// Round 14
// 1351.436 us; speedup vs baseline: 1.0359x; 1.0359x over previous
//
#include <hip/hip_runtime.h>
#include <hip/hip_bf16.h>

// Problem dims
constexpr int NB = 32, NS = 512, NE = 256, NC = 128, NHD = 256, NG = 1024, NT = 16, NH = 512;

typedef float f32x4 __attribute__((ext_vector_type(4)));
typedef short bf16x8 __attribute__((ext_vector_type(8)));

// ---------------- helpers ----------------
__device__ __forceinline__ unsigned short f2bf(float f) {
    unsigned u = __float_as_uint(f);
    u += 0x7fffu + ((u >> 16) & 1u);
    return (unsigned short)(u >> 16);
}
__device__ __forceinline__ float bf2f(unsigned short s) {
    return __uint_as_float(((unsigned)s) << 16);
}
__device__ __forceinline__ float vexp2(float x) {
    float r; asm("v_exp_f32 %0, %1" : "=v"(r) : "v"(x)); return r;
}
__device__ __forceinline__ float vrcp(float x) {
    float r; asm("v_rcp_f32 %0, %1" : "=v"(r) : "v"(x)); return r;
}
__device__ __forceinline__ float vlog2(float x) {
    float r; asm("v_log_f32 %0, %1" : "=v"(r) : "v"(x)); return r;
}
__device__ __forceinline__ unsigned char f2fp8(float v) {
    int r = __builtin_amdgcn_cvt_pk_fp8_f32(v, 0.f, 0, false);
    return (unsigned char)(r & 0xff);
}
// gate pre-activation scale factors (i,f,o: sigm -> -log2(e); g: tanh -> +2*log2(e))
__device__ __constant__ float KSC[4] = {-1.442695041f, -1.442695041f, 2.885390082f, -1.442695041f};

// ---------------- prep kernels ----------------
// wT[e3][c] = conv_w[c][e3]   (e3 = e*3+k, 768x128)
__global__ void k_prep_convw(const float* __restrict__ w, float* __restrict__ wT) {
    int i = blockIdx.x * 256 + threadIdx.x;
    if (i >= 768 * 128) return;
    int e3 = i >> 7, c = i & 127;
    wT[i] = w[c * 768 + e3];
}

// per-(cell,gate)-column absmax scale: scale[d][j*4+g] = max_k |whh| / 448
__global__ void k_prep_scale(const float* __restrict__ whh_f, const float* __restrict__ whh_b,
                             float* __restrict__ scale) {
    int d = blockIdx.y;
    const float* src = d ? whh_b : whh_f;
    int col = blockIdx.x * 256 + threadIdx.x;
    if (col >= 1024) return;
    int j = col >> 2, g = col & 3;
    const float* p = src + (size_t)(g * 256 + j) * 256;
    float m = 0.f;
    for (int k = 0; k < 256; ++k) m = fmaxf(m, fabsf(p[k]));
    scale[d * 1024 + col] = (m > 0.f) ? (m * (1.f / 448.f)) : 1.f;
}

// fp8 MFMA B-fragment layout for whh (16-wave lstm):
// idx bits (LSB->MSB): e:3 | lane:6 | g:2 | kt:3 | w:4 | d:1
// j = w*16 + (lane&15); k = kt*32 + (lane>>4)*8 + e
__global__ void k_prep_whh_frag8(const float* __restrict__ whh_f, const float* __restrict__ whh_b,
                                 const float* __restrict__ scale, unsigned char* __restrict__ whhF8) {
    int i = blockIdx.x * 256 + threadIdx.x;
    if (i >= (1 << 19)) return;
    int e = i & 7;
    int lane = (i >> 3) & 63;
    int g = (i >> 9) & 3;
    int kt = (i >> 11) & 7;
    int w = (i >> 14) & 15;
    int d = (i >> 18) & 1;
    const float* src = d ? whh_b : whh_f;
    int j = w * 16 + (lane & 15);
    int k = kt * 32 + (lane >> 4) * 8 + e;
    float sc = scale[d * 1024 + j * 4 + g];
    float v = src[(g * 256 + j) * 256 + k] / sc;
    whhF8[i] = f2fp8(v);
}

// bf16 MFMA A-fragment layout for wih (xgate transpose-GEMM; rows = gate-cols):
// idx = ((((d*64 + ctg)*4 + kt)*64 + lane)*8 + e)
// row = lane&15 -> cell = ctg*4 + (row>>2), g = row&3; k = kt*32 + (lane>>4)*8 + e
// value = bf16( wih_d[(g*256+cell)*128 + k] * KSC[g] )
__global__ void k_prep_wih_frag(const float* __restrict__ wih_f, const float* __restrict__ wih_b,
                                unsigned short* __restrict__ wihF) {
    int i = blockIdx.x * 256 + threadIdx.x;
    if (i >= (1 << 18)) return;
    int e = i & 7;
    int lane = (i >> 3) & 63;
    int kt = (i >> 9) & 3;
    int ctg = (i >> 11) & 63;
    int d = (i >> 17) & 1;
    const float* src = d ? wih_b : wih_f;
    int row = lane & 15;
    int cell = ctg * 4 + (row >> 2), g = row & 3;
    int k = kt * 32 + (lane >> 4) * 8 + e;
    wihF[i] = f2bf(src[(g * 256 + cell) * 128 + k] * KSC[g]);
}

// bias2s[d][j*4+g] = (bih[g*256+j] + bhh[g*256+j]) * KSC[g]
__global__ void k_prep_bias(const float* __restrict__ bih_f, const float* __restrict__ bhh_f,
                            const float* __restrict__ bih_b, const float* __restrict__ bhh_b,
                            float* __restrict__ bias2s) {
    int d = blockIdx.y;
    const float* bi = d ? bih_b : bih_f;
    const float* bh = d ? bhh_b : bhh_f;
    int i = blockIdx.x * 256 + threadIdx.x;
    if (i >= NG) return;
    int g = i & 3, j = i >> 2;
    bias2s[(size_t)d * NG + i] = (bi[g * 256 + j] + bh[g * 256 + j]) * KSC[g];
}

// ---------------- embedding + conv1d(k=3,pad=1) + relu -> bf16 feat ----------------
__global__ __launch_bounds__(128) void k_conv(const int* __restrict__ x,
                                              const float* __restrict__ table,
                                              const float* __restrict__ wT,
                                              const float* __restrict__ conv_b,
                                              unsigned short* __restrict__ feat) {
    int b = blockIdx.y;
    int s0 = blockIdx.x * 8;
    int c = threadIdx.x;
    __shared__ float win[10][NE];
    for (int i = 0; i < 10; ++i) {
        int s = s0 - 1 + i;
        if (s < 0 || s >= NS) {
            for (int e = c; e < NE; e += 128) win[i][e] = 0.f;
        } else {
            int tok = x[b * NS + s];
            const float* row = table + (size_t)tok * NE;
            for (int e = c; e < NE; e += 128) win[i][e] = row[e];
        }
    }
    __syncthreads();
    float acc[8];
    float bc = conv_b[c];
#pragma unroll
    for (int p = 0; p < 8; ++p) acc[p] = bc;
    for (int e = 0; e < NE; ++e) {
        float r[10];
#pragma unroll
        for (int i = 0; i < 10; ++i) r[i] = win[i][e];
#pragma unroll
        for (int k = 0; k < 3; ++k) {
            float wv = wT[(e * 3 + k) * NC + c];
#pragma unroll
            for (int p = 0; p < 8; ++p) acc[p] += wv * r[p + k];
        }
    }
#pragma unroll
    for (int p = 0; p < 8; ++p) {
        feat[((size_t)b * NS + s0 + p) * NC + c] = f2bf(fmaxf(acc[p], 0.f));
    }
}

// ---------------- input-side gates via bf16 MFMA transpose-GEMM ----------------
// Computes xg^T: A = wih (16 gate-cols x K), B = feat (K x 16 pairs).
// C-layout (m89): row=(lane>>4)*4+reg, col=lane&15 -> lane holds ALL 4 GATES of
// cell (ctg*4+lq) for pair (p0+l15) -> one packed u64 store into the xg layout
// the LSTM already reads. No LDS, no barriers.
__global__ __launch_bounds__(256) void k_xgate(const unsigned short* __restrict__ feat,
                                               const unsigned short* __restrict__ wihF,
                                               const float* __restrict__ bias2s,
                                               unsigned short* __restrict__ xg) {
    int d = blockIdx.y;
    int p0 = blockIdx.x * 16;
    int tid = threadIdx.x;
    int w = tid >> 6, l = tid & 63;
    int l15 = l & 15, lq = l >> 4;
    // B-frags: feat rows for this lane's pair, 4 K-steps (reused across 16 ctiles)
    int p = p0 + l15, b = p & 31, s = p >> 5;
    const unsigned short* fp = feat + ((size_t)b * NS + s) * NC + lq * 8;
    bf16x8 bf[4];
#pragma unroll
    for (int kt = 0; kt < 4; ++kt) bf[kt] = *(const bf16x8*)(fp + kt * 32);
    const unsigned short* WF = wihF + ((size_t)d << 17);
    unsigned short* XGD = xg + (size_t)d * NS * NB * NG;
#pragma unroll
    for (int ct = 0; ct < 16; ++ct) {
        int ctg = w * 16 + ct;
        int cell = ctg * 4 + lq;
        float4 bv = *(const float4*)(bias2s + (size_t)d * NG + cell * 4);
        f32x4 acc = {bv.x, bv.y, bv.z, bv.w};
#pragma unroll
        for (int kt = 0; kt < 4; ++kt) {
            bf16x8 af = *(const bf16x8*)(WF + (((size_t)ctg * 4 + kt) * 64 + l) * 8);
            acc = __builtin_amdgcn_mfma_f32_16x16x32_bf16(af, bf[kt], acc, 0, 0, 0);
        }
        unsigned long long hp = (unsigned long long)f2bf(acc[0])
                              | ((unsigned long long)f2bf(acc[1]) << 16)
                              | ((unsigned long long)f2bf(acc[2]) << 32)
                              | ((unsigned long long)f2bf(acc[3]) << 48);
        *(unsigned long long*)(XGD + (size_t)p * 1024 + cell * 4) = hp;
    }
}

// ---------------- LSTM recurrence: fp8 MFMA, W register-resident, 4-block M=16 ----------
// (round-12 config — best measured; round-13 8-way split was issue-neutral)
__global__ __launch_bounds__(1024, 1) void k_lstm2(const unsigned char* __restrict__ whhF8,
                                                   const float* __restrict__ scale,
                                                   const unsigned short* __restrict__ xg,
                                                   unsigned short* __restrict__ hcat) {
    int bid = blockIdx.x;
    int d = bid >> 1, bh = bid & 1;
    int tid = threadIdx.x;
    int w = tid >> 6, l = tid & 63;
    int l15 = l & 15, lq = l >> 4;
    __shared__ unsigned char hbuf[2][16][280];
    for (int i = tid; i < 2 * 16 * 280; i += 1024) (&hbuf[0][0][0])[i] = 0;
    unsigned long long wf[32];
    const unsigned char* wp = whhF8 + ((size_t)(d * 16 + w) << 14) + (size_t)l * 8;
#pragma unroll
    for (int f = 0; f < 32; ++f) wf[f] = *(const unsigned long long*)(wp + f * 512);
    int cell = w * 16 + l15;
    float csc[4];
#pragma unroll
    for (int g = 0; g < 4; ++g)
        csc[g] = scale[d * 1024 + cell * 4 + g] * KSC[g];
    const unsigned short* XG = xg + (size_t)d * NS * NB * NG;
    float cst[4] = {};
    __syncthreads();
    int cur = 0;
    unsigned long long xq[4];
    {
        int s0 = d ? (NS - 1) : 0;
#pragma unroll
        for (int r = 0; r < 4; ++r)
            xq[r] = *(const unsigned long long*)(
                XG + (size_t)(s0 * 32 + bh * 16 + lq * 4 + r) * 1024 + cell * 4);
    }
    for (int step = 0; step < NS; ++step) {
        int s = d ? (NS - 1 - step) : step;
        unsigned long long xn[4];
        {
            int stn = (step + 1 < NS) ? step + 1 : step;
            int sn = d ? (NS - 1 - stn) : stn;
#pragma unroll
            for (int r = 0; r < 4; ++r)
                xn[r] = *(const unsigned long long*)(
                    XG + (size_t)(sn * 32 + bh * 16 + lq * 4 + r) * 1024 + cell * 4);
        }
        f32x4 acc[4];
#pragma unroll
        for (int g = 0; g < 4; ++g) acc[g] = (f32x4){0.f, 0.f, 0.f, 0.f};
#pragma unroll
        for (int kt = 0; kt < 8; ++kt) {
            unsigned long long a = *(const unsigned long long*)&hbuf[cur][l15][kt * 32 + lq * 8];
#pragma unroll
            for (int g = 0; g < 4; ++g)
                acc[g] = __builtin_amdgcn_mfma_f32_16x16x32_fp8_fp8(
                    (long long)a, (long long)wf[kt * 4 + g], acc[g], 0, 0, 0);
        }
        int nxt = cur ^ 1;
#pragma unroll
        for (int r = 0; r < 4; ++r) {
            unsigned long long xv = xq[r];
            float pi = fmaf(acc[0][r], csc[0], bf2f((unsigned short)xv));
            float pf = fmaf(acc[1][r], csc[1], bf2f((unsigned short)(xv >> 16)));
            float pg = fmaf(acc[2][r], csc[2], bf2f((unsigned short)(xv >> 32)));
            float po = fmaf(acc[3][r], csc[3], bf2f((unsigned short)(xv >> 48)));
            float si = vrcp(1.f + vexp2(pi));
            float sf = vrcp(1.f + vexp2(pf));
            float tg = fmaf(-2.f, vrcp(1.f + vexp2(pg)), 1.f);
            float so = vrcp(1.f + vexp2(po));
            float c = fmaf(sf, cst[r], si * tg);
            cst[r] = c;
            float tc = fmaf(-2.f, vrcp(1.f + vexp2(2.885390082f * c)), 1.f);
            float h = so * tc;
            int b = lq * 4 + r;
            __builtin_nontemporal_store(f2bf(h),
                hcat + (size_t)(s * 32 + bh * 16 + b) * NH + d * NHD + cell);
            hbuf[nxt][b][cell] = f2fp8(h);
        }
        __syncthreads();
        cur = nxt;
#pragma unroll
        for (int r = 0; r < 4; ++r) xq[r] = xn[r];
    }
}

// ---------------- FC to emissions: em[s][b][t]  (hcat is bf16) ----------------
__global__ __launch_bounds__(256) void k_fc(const unsigned short* __restrict__ hcat,
                                            const float* __restrict__ fc_w,
                                            const float* __restrict__ fc_b,
                                            float* __restrict__ em) {
    int p0 = blockIdx.x * 16;
    __shared__ float hv[16][NH];
    for (int i = threadIdx.x; i < 16 * NH; i += 256) {
        int p = i >> 9, hh = i & 511;
        hv[p][hh] = bf2f(hcat[(size_t)(p0 + p) * NH + hh]);
    }
    __syncthreads();
    int p = threadIdx.x >> 4, t = threadIdx.x & 15;
    const float* fw = fc_w + t * NH;
    float acc = fc_b[t];
#pragma unroll 8
    for (int hh = 0; hh < NH; ++hh) acc += hv[p][hh] * fw[hh];
    em[(size_t)(p0 + p) * NT + t] = acc;
}

// ---------------- CRF NLL per batch: wave-parallel forward algorithm ----------------
__global__ __launch_bounds__(64) void k_crf(const float* __restrict__ em,
                                            const int* __restrict__ tags,
                                            const int* __restrict__ mask,
                                            const float* __restrict__ start_t,
                                            const float* __restrict__ end_t,
                                            const float* __restrict__ trans,
                                            float* __restrict__ res) {
    int b = blockIdx.x;
    int tid = threadIdx.x;
    __shared__ float em_sh[NS * NT];
    __shared__ float tr[NT * NT];
    __shared__ float alpha_sh[NT];
    __shared__ float msk[NS];
    __shared__ float sc_sh;
    for (int i = tid; i < NT * NT; i += 64) tr[i] = trans[i];
    for (int i = tid; i < NS * NT; i += 64) {
        int s = i >> 4, t = i & 15;
        em_sh[i] = em[((size_t)s * NB + b) * NT + t];
    }
    for (int s = tid; s < NS; s += 64) msk[s] = (float)mask[b * NS + s];
    __syncthreads();
    float part = 0.f, msum = 0.f;
    for (int s = tid; s < NS; s += 64) msum += msk[s];
    for (int s = 1 + tid; s < NS; s += 64) {
        int pv = tags[b * NS + s - 1], cu = tags[b * NS + s];
        part += (tr[pv * NT + cu] + em_sh[s * NT + cu]) * msk[s];
    }
#pragma unroll
    for (int o = 32; o > 0; o >>= 1) {
        part += __shfl_down(part, o);
        msum += __shfl_down(msum, o);
    }
    if (tid == 0) {
        int t0 = tags[b * NS];
        int send = (int)msum - 1;
        sc_sh = start_t[t0] + em_sh[t0] + part + end_t[tags[b * NS + send]];
    }
    if (tid < NT) alpha_sh[tid] = start_t[tid] + em_sh[tid];
    __syncthreads();
    int t_to = tid >> 2, q = tid & 3;
    for (int s = 1; s < NS; ++s) {
        float v0 = alpha_sh[q * 4 + 0] + tr[(q * 4 + 0) * NT + t_to];
        float v1 = alpha_sh[q * 4 + 1] + tr[(q * 4 + 1) * NT + t_to];
        float v2 = alpha_sh[q * 4 + 2] + tr[(q * 4 + 2) * NT + t_to];
        float v3 = alpha_sh[q * 4 + 3] + tr[(q * 4 + 3) * NT + t_to];
        float mx = fmaxf(fmaxf(v0, v1), fmaxf(v2, v3));
        mx = fmaxf(mx, __shfl_xor(mx, 1));
        mx = fmaxf(mx, __shfl_xor(mx, 2));
        float nmx = -1.442695041f * mx;
        float ss = vexp2(fmaf(v0, 1.442695041f, nmx)) + vexp2(fmaf(v1, 1.442695041f, nmx))
                 + vexp2(fmaf(v2, 1.442695041f, nmx)) + vexp2(fmaf(v3, 1.442695041f, nmx));
        ss += __shfl_xor(ss, 1);
        ss += __shfl_xor(ss, 2);
        float nv = mx + 0.6931471806f * vlog2(ss) + em_sh[s * NT + t_to];
        float old = alpha_sh[t_to];
        nv = (msk[s] > 0.f) ? nv : old;
        __syncthreads();
        if (q == 0) alpha_sh[t_to] = nv;
        __syncthreads();
    }
    if (tid == 0) {
        float mx = -1e30f;
        for (int t = 0; t < NT; ++t) mx = fmaxf(mx, alpha_sh[t] + end_t[t]);
        float sum = 0.f;
        for (int t = 0; t < NT; ++t) sum += vexp2(1.442695041f * (alpha_sh[t] + end_t[t] - mx));
        res[b] = sc_sh - (mx + 0.6931471806f * vlog2(sum));
    }
}

__global__ void k_final(const float* __restrict__ res, float* __restrict__ out) {
    int tid = threadIdx.x;
    float v = (tid < NB) ? res[tid] : 0.f;
#pragma unroll
    for (int o = 32; o > 0; o >>= 1) v += __shfl_down(v, o);
    if (tid == 0) out[0] = -v / NB;
}

// ---------------- workspace layout ----------------
constexpr size_t SZ_FEAT  = (size_t)NB * NS * NC * 2;       // 4 MB (bf16)
constexpr size_t SZ_WT    = (size_t)768 * 128 * 4;          // 384 KB
constexpr size_t SZ_WHHF8 = (size_t)(1 << 19);              // 512 KB (fp8 frags)
constexpr size_t SZ_SCALE = (size_t)2 * 1024 * 4;           // 8 KB
constexpr size_t SZ_WIHF  = (size_t)(1 << 18) * 2;          // 512 KB (bf16 A-frags)
constexpr size_t SZ_BIAS  = (size_t)2 * NG * 4;             // 8 KB
constexpr size_t SZ_XG    = (size_t)2 * NS * NB * NG * 2;   // 64 MB (bf16)
constexpr size_t SZ_HCAT  = (size_t)NS * NB * NH * 2;       // 16 MB (bf16)
constexpr size_t SZ_EM    = (size_t)NS * NB * NT * 4;       // 1 MB

constexpr size_t OFF_FEAT  = 0;
constexpr size_t OFF_WT    = OFF_FEAT + SZ_FEAT;
constexpr size_t OFF_WHHF8 = OFF_WT + SZ_WT;
constexpr size_t OFF_SCALE = OFF_WHHF8 + SZ_WHHF8;
constexpr size_t OFF_WIHF  = OFF_SCALE + SZ_SCALE;
constexpr size_t OFF_BIAS  = OFF_WIHF + SZ_WIHF;
constexpr size_t OFF_XG    = OFF_BIAS + SZ_BIAS;
constexpr size_t OFF_HCAT  = OFF_XG + SZ_XG;
constexpr size_t OFF_EM    = OFF_HCAT + SZ_HCAT;
constexpr size_t OFF_RES   = OFF_EM + SZ_EM;

extern "C" void kernel_launch(void* const* d_in, const int* in_sizes, int n_in,
                              void* d_out, int out_size, void* d_ws, size_t ws_size,
                              hipStream_t stream) {
    const int* x        = (const int*)d_in[0];
    const int* mask     = (const int*)d_in[1];
    const int* tags     = (const int*)d_in[2];
    const float* table  = (const float*)d_in[3];
    const float* conv_w = (const float*)d_in[4];
    const float* conv_b = (const float*)d_in[5];
    const float* wih_f  = (const float*)d_in[6];
    const float* whh_f  = (const float*)d_in[7];
    const float* bih_f  = (const float*)d_in[8];
    const float* bhh_f  = (const float*)d_in[9];
    const float* wih_b  = (const float*)d_in[10];
    const float* whh_b  = (const float*)d_in[11];
    const float* bih_b  = (const float*)d_in[12];
    const float* bhh_b  = (const float*)d_in[13];
    const float* fc_w   = (const float*)d_in[14];
    const float* fc_b   = (const float*)d_in[15];
    const float* start_t = (const float*)d_in[16];
    const float* end_t  = (const float*)d_in[17];
    const float* trans  = (const float*)d_in[18];

    char* ws = (char*)d_ws;
    unsigned short* feat = (unsigned short*)(ws + OFF_FEAT);
    float* wT   = (float*)(ws + OFF_WT);
    unsigned char* whhF8 = (unsigned char*)(ws + OFF_WHHF8);
    float* scale = (float*)(ws + OFF_SCALE);
    unsigned short* wihF = (unsigned short*)(ws + OFF_WIHF);
    float* bias2s = (float*)(ws + OFF_BIAS);
    unsigned short* xg = (unsigned short*)(ws + OFF_XG);
    unsigned short* hcat = (unsigned short*)(ws + OFF_HCAT);
    float* em   = (float*)(ws + OFF_EM);
    float* res  = (float*)(ws + OFF_RES);

    k_prep_convw<<<dim3(384), 256, 0, stream>>>(conv_w, wT);
    k_prep_scale<<<dim3(4, 2), 256, 0, stream>>>(whh_f, whh_b, scale);
    k_prep_whh_frag8<<<dim3(2048), 256, 0, stream>>>(whh_f, whh_b, scale, whhF8);
    k_prep_wih_frag<<<dim3(1024), 256, 0, stream>>>(wih_f, wih_b, wihF);
    k_prep_bias<<<dim3(4, 2), 256, 0, stream>>>(bih_f, bhh_f, bih_b, bhh_b, bias2s);
    k_conv<<<dim3(NS / 8, NB), 128, 0, stream>>>(x, table, wT, conv_b, feat);
    k_xgate<<<dim3(NS * NB / 16, 2), 256, 0, stream>>>(feat, wihF, bias2s, xg);
    k_lstm2<<<dim3(4), 1024, 0, stream>>>(whhF8, scale, xg, hcat);
    k_fc<<<dim3(NS * NB / 16), 256, 0, stream>>>(hcat, fc_w, fc_b, em);
    k_crf<<<dim3(NB), 64, 0, stream>>>(em, tags, mask, start_t, end_t, trans, res);
    k_final<<<dim3(1), 64, 0, stream>>>(res, (float*)d_out);
}